// Round 3
// baseline (188.511 us; speedup 1.0000x reference)
//
#include <hip/hip_runtime.h>
#include <hip/hip_bf16.h>
#include <cstdint>
#include <cstddef>

// Problem constants
#define BDIM   32768
#define KDIM   2048
#define NDIM   128
#define VHEADS 20
#define PDIM   6
#define RLORA  10

#define BK      64
#define NCHUNK  (KDIM / BK)                 // 32
#define OUT_ELEMS   (BDIM * VHEADS * PDIM)  // 3932160
#define WS_W_ELEMS  (KDIM * NDIM)           // 262144 bf16
#define WS_W_BYTES  (WS_W_ELEMS * 2)        // 524288

typedef __attribute__((ext_vector_type(8))) __bf16 bf16x8;
typedef __attribute__((ext_vector_type(4))) float f32x4;
typedef __attribute__((ext_vector_type(2))) float f32x2;
typedef __attribute__((ext_vector_type(4))) unsigned int u32x4;

union FragU { bf16x8 b; u32x4 u; };

__device__ __forceinline__ unsigned int cvt_pk_bf16(float lo, float hi) {
  unsigned int r;
  asm("v_cvt_pk_bf16_f32 %0, %1, %2" : "=v"(r) : "v"(lo), "v"(hi));
  return r;
}

__device__ __forceinline__ float fast_tanh(float x) {
  float ax = fabsf(x);
  float e  = __expf(-2.0f * ax);
  float t  = __fdividef(1.0f - e, 1.0f + e);
  return copysignf(t, x);
}

// ---------------------------------------------------------------------------
// k0: pack We1 f32[2048][128] -> bf16 in B-FRAGMENT-MAJOR order:
//   flat[(((c*8+nt)*2+ks)*64 + lane)*8 + j] = bf16(We1[k][n])
//   with n = nt*16 + (lane&15), k = c*64 + ks*32 + (lane>>4)*8 + j.
// So in k1, B-load for (c,nt,ks) is a single coalesced dwordx4 at
//   wp + (c*16 + nt*2 + ks)*1024B + lane*16B.
// Also computes M = lora_A @ lora_B  ([2][120]).
// ---------------------------------------------------------------------------
__global__ __launch_bounds__(256)
void k0_pack(const float* __restrict__ We1,
             const float* __restrict__ lA,
             const float* __restrict__ lB,
             unsigned short* __restrict__ wsw,
             float* __restrict__ wsM) {
  if (blockIdx.x == 128) {
    int t = threadIdx.x;
    if (t < 2 * VHEADS * PDIM) {
      int d  = t / (VHEADS * PDIM);
      int vp = t - d * (VHEADS * PDIM);
      float s = 0.f;
#pragma unroll
      for (int r = 0; r < RLORA; ++r)
        s = fmaf(lA[d * RLORA + r], lB[r * (VHEADS * PDIM) + vp], s);
      wsM[t] = s;  // layout [d][vp]
    }
    return;
  }
  int t    = blockIdx.x * 256 + threadIdx.x;  // 0..32767
  int lane = t & 63;
  int blk  = t >> 6;                          // 0..511
  int ks   = blk & 1;
  int nt   = (blk >> 1) & 7;
  int c    = blk >> 4;
  int n    = nt * 16 + (lane & 15);
  int kb   = c * BK + ks * 32 + (lane >> 4) * 8;

  unsigned int u[4];
#pragma unroll
  for (int q = 0; q < 4; ++q) {
    float f0 = We1[(size_t)(kb + 2 * q + 0) * NDIM + n];
    float f1 = We1[(size_t)(kb + 2 * q + 1) * NDIM + n];
    __hip_bfloat16 h0 = __float2bfloat16(f0);
    __hip_bfloat16 h1 = __float2bfloat16(f1);
    u[q] = (unsigned int)*reinterpret_cast<unsigned short*>(&h0) |
           ((unsigned int)*reinterpret_cast<unsigned short*>(&h1) << 16);
  }
  *reinterpret_cast<u32x4*>(wsw + (size_t)t * 8) = u32x4{u[0], u[1], u[2], u[3]};
}

// ---------------------------------------------------------------------------
// k1: fused encoder + heads.
//   GEMM: 512 blocks x 256 thr (4 waves), 64 rows/block, 16 rows/wave.
//     A (x rows): nontemporal f32 global -> cvt_pk bf16 frags (no reuse).
//     B (We1):    fragment-packed bf16 from ws, direct global loads (L2-hot).
//     No LDS staging, no barriers in the main loop -> deep pipelining.
//   Epilogue: +be1, relu, @We2, +be2 -> z; broadcast z via 512B LDS.
//   Heads: per (lane=row, wave+i = head), wave-uniform v -> scalar wt loads.
// ---------------------------------------------------------------------------
__global__ __launch_bounds__(256, 2)
void k1_fused(const float* __restrict__ x,
              const unsigned short* __restrict__ wp,
              const float* __restrict__ be1,
              const float* __restrict__ We2,
              const float* __restrict__ be2,
              const float* __restrict__ W1,
              const float* __restrict__ b1,
              const float* __restrict__ W2,
              const float* __restrict__ b2,
              const float* __restrict__ M,
              float* __restrict__ out,
              float* __restrict__ zout) {
  __shared__ float zsh[64][2];

  const int tid  = threadIdx.x;
  const int lane = tid & 63;
  const int wv   = tid >> 6;   // 0..3
  const int l15  = lane & 15;
  const int kgrp = lane >> 4;  // 0..3
  const int blk  = blockIdx.x;
  const int rbase = blk * 64 + wv * 16;

  const float* aptr = x + (size_t)(rbase + l15) * KDIM + kgrp * 8;
  const char*  bptr = (const char*)wp + lane * 16;

  f32x4 acc[8];
#pragma unroll
  for (int i = 0; i < 8; ++i) acc[i] = f32x4{0.f, 0.f, 0.f, 0.f};

#pragma unroll 2
  for (int c = 0; c < NCHUNK; ++c) {
    const float* p = aptr + c * BK;
    f32x4 A0 = __builtin_nontemporal_load((const f32x4*)(p));
    f32x4 A1 = __builtin_nontemporal_load((const f32x4*)(p + 4));
    f32x4 A2 = __builtin_nontemporal_load((const f32x4*)(p + 32));
    f32x4 A3 = __builtin_nontemporal_load((const f32x4*)(p + 36));
    FragU a0, a1;
    a0.u = u32x4{cvt_pk_bf16(A0.x, A0.y), cvt_pk_bf16(A0.z, A0.w),
                 cvt_pk_bf16(A1.x, A1.y), cvt_pk_bf16(A1.z, A1.w)};
    a1.u = u32x4{cvt_pk_bf16(A2.x, A2.y), cvt_pk_bf16(A2.z, A2.w),
                 cvt_pk_bf16(A3.x, A3.y), cvt_pk_bf16(A3.z, A3.w)};
    const char* bc = bptr + (size_t)c * 16384;
#pragma unroll
    for (int nt = 0; nt < 8; ++nt) {
      FragU b0, b1;
      b0.u = *(const u32x4*)(bc + nt * 2048);
      b1.u = *(const u32x4*)(bc + nt * 2048 + 1024);
      acc[nt] = __builtin_amdgcn_mfma_f32_16x16x32_bf16(a0.b, b0.b, acc[nt], 0, 0, 0);
      acc[nt] = __builtin_amdgcn_mfma_f32_16x16x32_bf16(a1.b, b1.b, acc[nt], 0, 0, 0);
    }
  }

  // epilogue: +be1, relu, @We2, +be2 -> z rows rbase..rbase+15
  float part[4][2];
#pragma unroll
  for (int j = 0; j < 4; ++j) { part[j][0] = 0.f; part[j][1] = 0.f; }
#pragma unroll
  for (int nt = 0; nt < 8; ++nt) {
    int col = nt * 16 + l15;
    float bb = be1[col];
    float w0 = We2[col * 2 + 0];
    float w1 = We2[col * 2 + 1];
#pragma unroll
    for (int j = 0; j < 4; ++j) {
      float h = acc[nt][j] + bb;
      h = h > 0.f ? h : 0.f;
      part[j][0] = fmaf(h, w0, part[j][0]);
      part[j][1] = fmaf(h, w1, part[j][1]);
    }
  }
#pragma unroll
  for (int m = 1; m < 16; m <<= 1) {
#pragma unroll
    for (int j = 0; j < 4; ++j) {
      part[j][0] += __shfl_xor(part[j][0], m, 64);
      part[j][1] += __shfl_xor(part[j][1], m, 64);
    }
  }
  if (l15 == 0) {
    float bz0 = be2[0], bz1 = be2[1];
#pragma unroll
    for (int j = 0; j < 4; ++j) {
      int rl = wv * 16 + kgrp * 4 + j;   // C row = (lane>>4)*4 + reg
      float zz0 = part[j][0] + bz0;
      float zz1 = part[j][1] + bz1;
      zsh[rl][0] = zz0;
      zsh[rl][1] = zz1;
      f32x2 zz = {zz0, zz1};
      *(f32x2*)(zout + (size_t)(blk * 64 + rl) * 2) = zz;
    }
  }
  __syncthreads();

  // heads: row = blk*64 + lane; head v = i*4 + wv (wave-uniform)
  const int wvu = __builtin_amdgcn_readfirstlane(wv);
  float z0 = zsh[lane][0];
  float z1 = zsh[lane][1];
  float* orow = out + (size_t)(blk * 64 + lane) * (VHEADS * PDIM);

#pragma unroll 1
  for (int i = 0; i < 5; ++i) {
    int v = i * 4 + wvu;
    const float* w1a = W1 + (size_t)(v * 2 + 0) * NDIM;
    const float* w1b = W1 + (size_t)(v * 2 + 1) * NDIM;
    const float* bb1 = b1 + (size_t)v * NDIM;
    const float* w2  = W2 + (size_t)v * NDIM * PDIM;

    float p[6] = {0.f, 0.f, 0.f, 0.f, 0.f, 0.f};
#pragma unroll 4
    for (int h = 0; h < NDIM; ++h) {
      float hv = fmaf(z0, w1a[h], fmaf(z1, w1b[h], bb1[h]));
      hv = hv > 0.f ? hv : 0.f;
#pragma unroll
      for (int j = 0; j < 6; ++j) p[j] = fmaf(hv, w2[h * 6 + j], p[j]);
    }
    float o[6];
#pragma unroll
    for (int j = 0; j < 6; ++j) {
      float t1 = fast_tanh(p[j] + b2[v * PDIM + j]);
      float lo = fmaf(z0, M[v * PDIM + j], z1 * M[VHEADS * PDIM + v * PDIM + j]);
      o[j] = fast_tanh(fmaf(0.15f, lo, t1));
    }
    float* op = orow + v * PDIM;
    f32x2 o01 = {o[0], o[1]};
    f32x2 o23 = {o[2], o[3]};
    f32x2 o45 = {o[4], o[5]};
    __builtin_nontemporal_store(o01, (f32x2*)(op + 0));
    __builtin_nontemporal_store(o23, (f32x2*)(op + 2));
    __builtin_nontemporal_store(o45, (f32x2*)(op + 4));
  }
}

// ---------------------------------------------------------------------------
extern "C" void kernel_launch(void* const* d_in, const int* in_sizes, int n_in,
                              void* d_out, int out_size, void* d_ws, size_t ws_size,
                              hipStream_t stream) {
  const float* x   = (const float*)d_in[0];
  const float* We1 = (const float*)d_in[1];
  const float* be1 = (const float*)d_in[2];
  const float* We2 = (const float*)d_in[3];
  const float* be2 = (const float*)d_in[4];
  const float* W1  = (const float*)d_in[5];
  const float* b1  = (const float*)d_in[6];
  const float* W2  = (const float*)d_in[7];
  const float* b2  = (const float*)d_in[8];
  const float* lA  = (const float*)d_in[9];
  const float* lB  = (const float*)d_in[10];

  float* out  = (float*)d_out;
  float* zout = out + OUT_ELEMS;                       // second tuple output
  unsigned short* wsw = (unsigned short*)d_ws;         // 512 KB bf16 W pack
  float* wsM = (float*)((char*)d_ws + WS_W_BYTES);     // 240 floats

  hipLaunchKernelGGL(k0_pack, dim3(129), dim3(256), 0, stream,
                     We1, lA, lB, wsw, wsM);
  hipLaunchKernelGGL(k1_fused, dim3(BDIM / 64), dim3(256), 0, stream,
                     x, wsw, be1, We2, be2, W1, b1, W2, b2, wsM, out, zout);
}

// Round 4
// 150.911 us; speedup vs baseline: 1.2492x; 1.2492x over previous
//
#include <hip/hip_runtime.h>
#include <hip/hip_bf16.h>
#include <cstdint>
#include <cstddef>

// Problem constants
#define BDIM   32768
#define KDIM   2048
#define NDIM   128
#define VHEADS 20
#define PDIM   6
#define RLORA  10

#define BK      64
#define NCHUNK  (KDIM / BK)                 // 32
#define OUT_ELEMS   (BDIM * VHEADS * PDIM)  // 3932160
#define WS_W_ELEMS  (KDIM * NDIM)           // 262144 bf16
#define WS_W_BYTES  (WS_W_ELEMS * 2)        // 524288

typedef __attribute__((ext_vector_type(8))) __bf16 bf16x8;
typedef __attribute__((ext_vector_type(4))) float f32x4;
typedef __attribute__((ext_vector_type(2))) float f32x2;
typedef __attribute__((ext_vector_type(4))) unsigned int u32x4;

union FragU { bf16x8 b; u32x4 u; };

__device__ __forceinline__ unsigned int cvt_pk_bf16(float lo, float hi) {
  unsigned int r;
  asm("v_cvt_pk_bf16_f32 %0, %1, %2" : "=v"(r) : "v"(lo), "v"(hi));
  return r;
}

__device__ __forceinline__ float fast_tanh(float x) {
  float ax = fabsf(x);
  float e  = __expf(-2.0f * ax);
  float t  = __fdividef(1.0f - e, 1.0f + e);
  return copysignf(t, x);
}

// ---------------------------------------------------------------------------
// k0: pack We1 f32[2048][128] -> bf16 in B-FRAGMENT-MAJOR order:
//   flat[(((c*8+nt)*2+ks)*64 + lane)*8 + j] = bf16(We1[k][n])
//   with n = nt*16 + (lane&15), k = c*64 + ks*32 + (lane>>4)*8 + j.
// In k1 the B-load for (c,nt,ks) is one coalesced dwordx4 at
//   wp + (c*16 + nt*2 + ks)*1024B + lane*16B.
// Also computes M = lora_A @ lora_B  ([2][120]).
// ---------------------------------------------------------------------------
__global__ __launch_bounds__(256)
void k0_pack(const float* __restrict__ We1,
             const float* __restrict__ lA,
             const float* __restrict__ lB,
             unsigned short* __restrict__ wsw,
             float* __restrict__ wsM) {
  if (blockIdx.x == 128) {
    int t = threadIdx.x;
    if (t < 2 * VHEADS * PDIM) {
      int d  = t / (VHEADS * PDIM);
      int vp = t - d * (VHEADS * PDIM);
      float s = 0.f;
#pragma unroll
      for (int r = 0; r < RLORA; ++r)
        s = fmaf(lA[d * RLORA + r], lB[r * (VHEADS * PDIM) + vp], s);
      wsM[t] = s;  // layout [d][vp]
    }
    return;
  }
  int t    = blockIdx.x * 256 + threadIdx.x;  // 0..32767
  int lane = t & 63;
  int blk  = t >> 6;                          // 0..511
  int ks   = blk & 1;
  int nt   = (blk >> 1) & 7;
  int c    = blk >> 4;
  int n    = nt * 16 + (lane & 15);
  int kb   = c * BK + ks * 32 + (lane >> 4) * 8;

  unsigned int u[4];
#pragma unroll
  for (int q = 0; q < 4; ++q) {
    float f0 = We1[(size_t)(kb + 2 * q + 0) * NDIM + n];
    float f1 = We1[(size_t)(kb + 2 * q + 1) * NDIM + n];
    __hip_bfloat16 h0 = __float2bfloat16(f0);
    __hip_bfloat16 h1 = __float2bfloat16(f1);
    u[q] = (unsigned int)*reinterpret_cast<unsigned short*>(&h0) |
           ((unsigned int)*reinterpret_cast<unsigned short*>(&h1) << 16);
  }
  *reinterpret_cast<u32x4*>(wsw + (size_t)t * 8) = u32x4{u[0], u[1], u[2], u[3]};
}

// ---------------------------------------------------------------------------
// k1: fused encoder + heads, 4-way K-split for occupancy.
//   512 blocks x 1024 threads = 16 waves: wave = (wk 0..3 K-quarter, wr 0..3
//   row-group).  Each wave: 16 rows x 128 cols x 512 K partial via MFMA,
//   A direct from HBM (nontemporal f32 -> cvt_pk bf16), B fragment-packed
//   bf16 direct from L2 (no LDS staging, no barriers in main loop).
//   Then 2-stage LDS tree-reduce over wk, epilogue (be1,relu,We2,be2 -> z),
//   z broadcast via LDS, fused heads (head = wave-uniform, row = lane).
// ---------------------------------------------------------------------------
__global__ __launch_bounds__(1024, 8)
void k1_fused(const float* __restrict__ x,
              const unsigned short* __restrict__ wp,
              const float* __restrict__ be1,
              const float* __restrict__ We2,
              const float* __restrict__ be2,
              const float* __restrict__ W1,
              const float* __restrict__ b1,
              const float* __restrict__ W2,
              const float* __restrict__ b2,
              const float* __restrict__ M,
              float* __restrict__ out,
              float* __restrict__ zout) {
  // [q][row-group][16 rows][132 padded cols] f32 partials (66 KB) + z bcast
  __shared__ float red[2][4][16][132];
  __shared__ float zsh[64][2];

  const int tid  = threadIdx.x;
  const int lane = tid & 63;
  const int wv   = tid >> 6;   // 0..15
  const int wr   = wv & 3;     // row-group
  const int wk   = wv >> 2;    // K-quarter
  const int l15  = lane & 15;
  const int kgrp = lane >> 4;  // 0..3
  const int blk  = blockIdx.x;

  const float* aptr = x + (size_t)(blk * 64 + wr * 16 + l15) * KDIM
                        + wk * 512 + kgrp * 8;
  const char*  bptr = (const char*)wp + (size_t)wk * 8 * 16384 + lane * 16;

  f32x4 acc[8];
#pragma unroll
  for (int i = 0; i < 8; ++i) acc[i] = f32x4{0.f, 0.f, 0.f, 0.f};

#pragma unroll 2
  for (int c = 0; c < 8; ++c) {
    const float* p = aptr + c * BK;
    f32x4 A0 = __builtin_nontemporal_load((const f32x4*)(p));
    f32x4 A1 = __builtin_nontemporal_load((const f32x4*)(p + 4));
    f32x4 A2 = __builtin_nontemporal_load((const f32x4*)(p + 32));
    f32x4 A3 = __builtin_nontemporal_load((const f32x4*)(p + 36));
    FragU a0, a1;
    a0.u = u32x4{cvt_pk_bf16(A0.x, A0.y), cvt_pk_bf16(A0.z, A0.w),
                 cvt_pk_bf16(A1.x, A1.y), cvt_pk_bf16(A1.z, A1.w)};
    a1.u = u32x4{cvt_pk_bf16(A2.x, A2.y), cvt_pk_bf16(A2.z, A2.w),
                 cvt_pk_bf16(A3.x, A3.y), cvt_pk_bf16(A3.z, A3.w)};
    const char* bc = bptr + (size_t)c * 16384;
#pragma unroll
    for (int nt = 0; nt < 8; ++nt) {
      FragU b0, b1;
      b0.u = *(const u32x4*)(bc + nt * 2048);
      b1.u = *(const u32x4*)(bc + nt * 2048 + 1024);
      acc[nt] = __builtin_amdgcn_mfma_f32_16x16x32_bf16(a0.b, b0.b, acc[nt], 0, 0, 0);
      acc[nt] = __builtin_amdgcn_mfma_f32_16x16x32_bf16(a1.b, b1.b, acc[nt], 0, 0, 0);
    }
  }

  // ---- cross-wave K reduction (acc layout: col = nt*16+l15, row = kgrp*4+j)
  if (wk >= 2) {
    int q = wk - 2;
#pragma unroll
    for (int nt = 0; nt < 8; ++nt)
#pragma unroll
      for (int j = 0; j < 4; ++j)
        red[q][wr][kgrp * 4 + j][nt * 16 + l15] = acc[nt][j];
  }
  __syncthreads();
  if (wk < 2) {
#pragma unroll
    for (int nt = 0; nt < 8; ++nt)
#pragma unroll
      for (int j = 0; j < 4; ++j)
        acc[nt][j] += red[wk][wr][kgrp * 4 + j][nt * 16 + l15];
  }
  __syncthreads();
  if (wk == 1) {
#pragma unroll
    for (int nt = 0; nt < 8; ++nt)
#pragma unroll
      for (int j = 0; j < 4; ++j)
        red[0][wr][kgrp * 4 + j][nt * 16 + l15] = acc[nt][j];
  }
  __syncthreads();

  if (wk == 0) {
#pragma unroll
    for (int nt = 0; nt < 8; ++nt)
#pragma unroll
      for (int j = 0; j < 4; ++j)
        acc[nt][j] += red[0][wr][kgrp * 4 + j][nt * 16 + l15];

    // epilogue: +be1, relu, @We2, +be2 -> z rows (blk*64 + wr*16 ..+15)
    float part[4][2];
#pragma unroll
    for (int j = 0; j < 4; ++j) { part[j][0] = 0.f; part[j][1] = 0.f; }
#pragma unroll
    for (int nt = 0; nt < 8; ++nt) {
      int col = nt * 16 + l15;
      float bb = be1[col];
      float w0 = We2[col * 2 + 0];
      float w1 = We2[col * 2 + 1];
#pragma unroll
      for (int j = 0; j < 4; ++j) {
        float h = acc[nt][j] + bb;
        h = h > 0.f ? h : 0.f;
        part[j][0] = fmaf(h, w0, part[j][0]);
        part[j][1] = fmaf(h, w1, part[j][1]);
      }
    }
#pragma unroll
    for (int m = 1; m < 16; m <<= 1) {
#pragma unroll
      for (int j = 0; j < 4; ++j) {
        part[j][0] += __shfl_xor(part[j][0], m, 64);
        part[j][1] += __shfl_xor(part[j][1], m, 64);
      }
    }
    if (l15 == 0) {
      float bz0 = be2[0], bz1 = be2[1];
#pragma unroll
      for (int j = 0; j < 4; ++j) {
        int rl = wr * 16 + kgrp * 4 + j;
        float zz0 = part[j][0] + bz0;
        float zz1 = part[j][1] + bz1;
        zsh[rl][0] = zz0;
        zsh[rl][1] = zz1;
        f32x2 zz = {zz0, zz1};
        *(f32x2*)(zout + (size_t)(blk * 64 + rl) * 2) = zz;
      }
    }
  }
  __syncthreads();

  // ---- heads: row = lane, head v = wave id (wave-uniform -> scalar weights)
  const int wvu = __builtin_amdgcn_readfirstlane(wv);
  float z0 = zsh[lane][0];
  float z1 = zsh[lane][1];
  float* orow = out + (size_t)(blk * 64 + lane) * (VHEADS * PDIM);

  auto head = [&](int v) {
    const float* w1a = W1 + (size_t)(v * 2 + 0) * NDIM;
    const float* w1b = W1 + (size_t)(v * 2 + 1) * NDIM;
    const float* bb1 = b1 + (size_t)v * NDIM;
    const float* w2  = W2 + (size_t)v * NDIM * PDIM;

    float p[6] = {0.f, 0.f, 0.f, 0.f, 0.f, 0.f};
#pragma unroll 4
    for (int h = 0; h < NDIM; ++h) {
      float hv = fmaf(z0, w1a[h], fmaf(z1, w1b[h], bb1[h]));
      hv = hv > 0.f ? hv : 0.f;
#pragma unroll
      for (int j = 0; j < 6; ++j) p[j] = fmaf(hv, w2[h * 6 + j], p[j]);
    }
    float o[6];
#pragma unroll
    for (int j = 0; j < 6; ++j) {
      float t1 = fast_tanh(p[j] + b2[v * PDIM + j]);
      float lo = fmaf(z0, M[v * PDIM + j], z1 * M[VHEADS * PDIM + v * PDIM + j]);
      o[j] = fast_tanh(fmaf(0.15f, lo, t1));
    }
    float* op = orow + v * PDIM;
    f32x2 o01 = {o[0], o[1]};
    f32x2 o23 = {o[2], o[3]};
    f32x2 o45 = {o[4], o[5]};
    __builtin_nontemporal_store(o01, (f32x2*)(op + 0));
    __builtin_nontemporal_store(o23, (f32x2*)(op + 2));
    __builtin_nontemporal_store(o45, (f32x2*)(op + 4));
  };

  head(wvu);                      // heads 0..15
  if (wvu < 4) head(16 + wvu);    // heads 16..19
}

// ---------------------------------------------------------------------------
extern "C" void kernel_launch(void* const* d_in, const int* in_sizes, int n_in,
                              void* d_out, int out_size, void* d_ws, size_t ws_size,
                              hipStream_t stream) {
  const float* x   = (const float*)d_in[0];
  const float* We1 = (const float*)d_in[1];
  const float* be1 = (const float*)d_in[2];
  const float* We2 = (const float*)d_in[3];
  const float* be2 = (const float*)d_in[4];
  const float* W1  = (const float*)d_in[5];
  const float* b1  = (const float*)d_in[6];
  const float* W2  = (const float*)d_in[7];
  const float* b2  = (const float*)d_in[8];
  const float* lA  = (const float*)d_in[9];
  const float* lB  = (const float*)d_in[10];

  float* out  = (float*)d_out;
  float* zout = out + OUT_ELEMS;                       // second tuple output
  unsigned short* wsw = (unsigned short*)d_ws;         // 512 KB bf16 W pack
  float* wsM = (float*)((char*)d_ws + WS_W_BYTES);     // 240 floats

  hipLaunchKernelGGL(k0_pack, dim3(129), dim3(256), 0, stream,
                     We1, lA, lB, wsw, wsM);
  hipLaunchKernelGGL(k1_fused, dim3(BDIM / 64), dim3(1024), 0, stream,
                     x, wsw, be1, We2, be2, W1, b1, W2, b2, wsM, out, zout);
}

// Round 5
// 116.926 us; speedup vs baseline: 1.6122x; 1.2907x over previous
//
#include <hip/hip_runtime.h>
#include <hip/hip_bf16.h>
#include <cstdint>
#include <cstddef>

// Problem constants
#define BDIM   32768
#define KDIM   2048
#define NDIM   128
#define VHEADS 20
#define PDIM   6
#define RLORA  10

#define BK      64
#define NCHUNK  (KDIM / BK)                 // 32
#define OUT_ELEMS   (BDIM * VHEADS * PDIM)  // 3932160
#define WS_W_BYTES  (KDIM * NDIM * 2)       // 524288

typedef __attribute__((ext_vector_type(8))) __bf16 bf16x8;
typedef __attribute__((ext_vector_type(4))) float f32x4;
typedef __attribute__((ext_vector_type(2))) float f32x2;
typedef __attribute__((ext_vector_type(4))) unsigned int u32x4;

union FragU { bf16x8 b; u32x4 u; };

__device__ __forceinline__ unsigned int cvt_pk_bf16(float lo, float hi) {
  unsigned int r;
  asm("v_cvt_pk_bf16_f32 %0, %1, %2" : "=v"(r) : "v"(lo), "v"(hi));
  return r;
}

__device__ __forceinline__ void gload_lds16(const void* g, void* l) {
  __builtin_amdgcn_global_load_lds(
      (const __attribute__((address_space(1))) void*)(g),
      (__attribute__((address_space(3))) void*)(l), 16, 0, 0);
}

__device__ __forceinline__ float fast_tanh(float x) {
  float ax = fabsf(x);
  float e  = __expf(-2.0f * ax);
  float t  = __fdividef(1.0f - e, 1.0f + e);
  return copysignf(t, x);
}

// ---------------------------------------------------------------------------
// k0: pack We1 f32[2048][128] -> bf16 in B-FRAGMENT-MAJOR order:
//   flat[(((c*8+nt)*2+ks)*64 + lane)*8 + j] = bf16(We1[k][n])
//   n = nt*16 + (lane&15), k = c*64 + ks*32 + (lane>>4)*8 + j.
// Also M = lora_A @ lora_B ([2][120]).
// ---------------------------------------------------------------------------
__global__ __launch_bounds__(256)
void k0_pack(const float* __restrict__ We1,
             const float* __restrict__ lA,
             const float* __restrict__ lB,
             unsigned short* __restrict__ wsw,
             float* __restrict__ wsM) {
  if (blockIdx.x == 128) {
    int t = threadIdx.x;
    if (t < 2 * VHEADS * PDIM) {
      int d  = t / (VHEADS * PDIM);
      int vp = t - d * (VHEADS * PDIM);
      float s = 0.f;
#pragma unroll
      for (int r = 0; r < RLORA; ++r)
        s = fmaf(lA[d * RLORA + r], lB[r * (VHEADS * PDIM) + vp], s);
      wsM[t] = s;  // layout [d][vp]
    }
    return;
  }
  int t    = blockIdx.x * 256 + threadIdx.x;  // 0..32767
  int lane = t & 63;
  int blk  = t >> 6;                          // 0..511
  int ks   = blk & 1;
  int nt   = (blk >> 1) & 7;
  int c    = blk >> 4;
  int n    = nt * 16 + (lane & 15);
  int kb   = c * BK + ks * 32 + (lane >> 4) * 8;

  unsigned int u[4];
#pragma unroll
  for (int q = 0; q < 4; ++q) {
    float f0 = We1[(size_t)(kb + 2 * q + 0) * NDIM + n];
    float f1 = We1[(size_t)(kb + 2 * q + 1) * NDIM + n];
    __hip_bfloat16 h0 = __float2bfloat16(f0);
    __hip_bfloat16 h1 = __float2bfloat16(f1);
    u[q] = (unsigned int)*reinterpret_cast<unsigned short*>(&h0) |
           ((unsigned int)*reinterpret_cast<unsigned short*>(&h1) << 16);
  }
  *reinterpret_cast<u32x4*>(wsw + (size_t)t * 8) = u32x4{u[0], u[1], u[2], u[3]};
}

// ---------------------------------------------------------------------------
// k1: fused encoder + heads.  m97-style double-buffered global_load_lds for
// BOTH operands (DMA queue = VGPR-free prefetch depth).
//   512 blocks x 256 thr (4 waves); 64 rows/block, full K per wave.
//   A chunk: f32 [64 rows][64 k] = 16 KB, XOR-swizzled LDS image realized by
//     pre-swizzling the per-lane GLOBAL source address (linear LDS dest).
//     LDS(row, slot) = A[row][slot ^ (row&7)] (16B slots, low 3 bits).
//   B chunk: fragment-packed bf16, 16 KB, linear (lane*16 reads).
//   One __syncthreads per chunk.  Epilogue: be1/relu/We2/be2 -> z;
//   fused heads (head v = i*4+wave, row = lane).
// ---------------------------------------------------------------------------
__global__ __launch_bounds__(256, 2)
void k1_fused(const float* __restrict__ x,
              const unsigned short* __restrict__ wp,
              const float* __restrict__ be1,
              const float* __restrict__ We2,
              const float* __restrict__ be2,
              const float* __restrict__ W1,
              const float* __restrict__ b1,
              const float* __restrict__ W2,
              const float* __restrict__ b2,
              const float* __restrict__ M,
              float* __restrict__ out,
              float* __restrict__ zout) {
  __shared__ char ldsA[2][16384] __attribute__((aligned(16)));
  __shared__ char ldsB[2][16384] __attribute__((aligned(16)));
  __shared__ float zsh[64][2];

  const int tid  = threadIdx.x;
  const int lane = tid & 63;
  const int wv   = tid >> 6;   // 0..3
  const int l15  = lane & 15;
  const int kgrp = lane >> 4;  // 0..3
  const int blk  = blockIdx.x;

  // --- staging addresses -------------------------------------------------
  // A: instr q stages rows wv*16 + q*4 + (lane>>4), slot lane&15 (swizzled src)
  const int arow_off = wv * 16 + (lane >> 4);        // + q*4
  const char* bsrc = (const char*)wp + lane * 16;    // + c*16384 + (wv*4+q)*1024

  f32x4 acc[8];
#pragma unroll
  for (int i = 0; i < 8; ++i) acc[i] = f32x4{0.f, 0.f, 0.f, 0.f};

  auto STAGE = [&](int b, int c) {
#pragma unroll
    for (int q = 0; q < 4; ++q) {
      int row = arow_off + q * 4;
      const float* asrc = x + ((size_t)(blk * 64 + row) * KDIM + c * BK
                               + (((l15 ^ (row & 7)) << 2)));
      gload_lds16(asrc, &ldsA[b][(wv * 4 + q) * 1024]);
    }
#pragma unroll
    for (int q = 0; q < 4; ++q) {
      gload_lds16(bsrc + (size_t)c * 16384 + (wv * 4 + q) * 1024,
                  &ldsB[b][(wv * 4 + q) * 1024]);
    }
  };

  auto COMPUTE = [&](int b) {
    const int row = wv * 16 + l15;
    const char* abase = &ldsA[b][row * 256];
    const int rx = (row & 7) << 4;
    f32x4 A0 = *(const f32x4*)(abase + (((kgrp * 2 + 0) << 4) ^ rx));
    f32x4 A1 = *(const f32x4*)(abase + (((kgrp * 2 + 1) << 4) ^ rx));
    f32x4 A2 = *(const f32x4*)(abase + 128 + (((kgrp * 2 + 0) << 4) ^ rx));
    f32x4 A3 = *(const f32x4*)(abase + 128 + (((kgrp * 2 + 1) << 4) ^ rx));
    FragU a0, a1;
    a0.u = u32x4{cvt_pk_bf16(A0.x, A0.y), cvt_pk_bf16(A0.z, A0.w),
                 cvt_pk_bf16(A1.x, A1.y), cvt_pk_bf16(A1.z, A1.w)};
    a1.u = u32x4{cvt_pk_bf16(A2.x, A2.y), cvt_pk_bf16(A2.z, A2.w),
                 cvt_pk_bf16(A3.x, A3.y), cvt_pk_bf16(A3.z, A3.w)};
    const char* bbase = &ldsB[b][lane * 16];
#pragma unroll
    for (int nt = 0; nt < 8; ++nt) {
      FragU b0, b1;
      b0.u = *(const u32x4*)(bbase + (nt * 2 + 0) * 1024);
      b1.u = *(const u32x4*)(bbase + (nt * 2 + 1) * 1024);
      acc[nt] = __builtin_amdgcn_mfma_f32_16x16x32_bf16(a0.b, b0.b, acc[nt], 0, 0, 0);
      acc[nt] = __builtin_amdgcn_mfma_f32_16x16x32_bf16(a1.b, b1.b, acc[nt], 0, 0, 0);
    }
  };

  // prologue
  STAGE(0, 0);
  __syncthreads();

#pragma unroll 2
  for (int c = 0; c < NCHUNK; ++c) {
    int b = c & 1;
    if (c + 1 < NCHUNK) STAGE(b ^ 1, c + 1);
    COMPUTE(b);
    __syncthreads();
  }

  // ---- epilogue: +be1, relu, @We2, +be2 -> z rows (blk*64 + wv*16 ..+15)
  float part[4][2];
#pragma unroll
  for (int j = 0; j < 4; ++j) { part[j][0] = 0.f; part[j][1] = 0.f; }
#pragma unroll
  for (int nt = 0; nt < 8; ++nt) {
    int col = nt * 16 + l15;
    float bb = be1[col];
    float w0 = We2[col * 2 + 0];
    float w1 = We2[col * 2 + 1];
#pragma unroll
    for (int j = 0; j < 4; ++j) {
      float h = acc[nt][j] + bb;
      h = h > 0.f ? h : 0.f;
      part[j][0] = fmaf(h, w0, part[j][0]);
      part[j][1] = fmaf(h, w1, part[j][1]);
    }
  }
#pragma unroll
  for (int m = 1; m < 16; m <<= 1) {
#pragma unroll
    for (int j = 0; j < 4; ++j) {
      part[j][0] += __shfl_xor(part[j][0], m, 64);
      part[j][1] += __shfl_xor(part[j][1], m, 64);
    }
  }
  if (l15 == 0) {
    float bz0 = be2[0], bz1 = be2[1];
#pragma unroll
    for (int j = 0; j < 4; ++j) {
      int rl = wv * 16 + kgrp * 4 + j;   // C row = (lane>>4)*4 + reg
      float zz0 = part[j][0] + bz0;
      float zz1 = part[j][1] + bz1;
      zsh[rl][0] = zz0;
      zsh[rl][1] = zz1;
      f32x2 zz = {zz0, zz1};
      *(f32x2*)(zout + (size_t)(blk * 64 + rl) * 2) = zz;
    }
  }
  __syncthreads();

  // ---- heads: row = lane, head v = i*4 + wv (wave-uniform -> scalar weights)
  const int wvu = __builtin_amdgcn_readfirstlane(wv);
  float z0 = zsh[lane][0];
  float z1 = zsh[lane][1];
  float* orow = out + (size_t)(blk * 64 + lane) * (VHEADS * PDIM);

#pragma unroll 1
  for (int i = 0; i < 5; ++i) {
    int v = i * 4 + wvu;
    const float* w1a = W1 + (size_t)(v * 2 + 0) * NDIM;
    const float* w1b = W1 + (size_t)(v * 2 + 1) * NDIM;
    const float* bb1 = b1 + (size_t)v * NDIM;
    const float* w2  = W2 + (size_t)v * NDIM * PDIM;

    float p[6] = {0.f, 0.f, 0.f, 0.f, 0.f, 0.f};
#pragma unroll 4
    for (int h = 0; h < NDIM; ++h) {
      float hv = fmaf(z0, w1a[h], fmaf(z1, w1b[h], bb1[h]));
      hv = hv > 0.f ? hv : 0.f;
#pragma unroll
      for (int j = 0; j < 6; ++j) p[j] = fmaf(hv, w2[h * 6 + j], p[j]);
    }
    float o[6];
#pragma unroll
    for (int j = 0; j < 6; ++j) {
      float t1 = fast_tanh(p[j] + b2[v * PDIM + j]);
      float lo = fmaf(z0, M[v * PDIM + j], z1 * M[VHEADS * PDIM + v * PDIM + j]);
      o[j] = fast_tanh(fmaf(0.15f, lo, t1));
    }
    float* op = orow + v * PDIM;
    f32x2 o01 = {o[0], o[1]};
    f32x2 o23 = {o[2], o[3]};
    f32x2 o45 = {o[4], o[5]};
    __builtin_nontemporal_store(o01, (f32x2*)(op + 0));
    __builtin_nontemporal_store(o23, (f32x2*)(op + 2));
    __builtin_nontemporal_store(o45, (f32x2*)(op + 4));
  }
}

// ---------------------------------------------------------------------------
extern "C" void kernel_launch(void* const* d_in, const int* in_sizes, int n_in,
                              void* d_out, int out_size, void* d_ws, size_t ws_size,
                              hipStream_t stream) {
  const float* x   = (const float*)d_in[0];
  const float* We1 = (const float*)d_in[1];
  const float* be1 = (const float*)d_in[2];
  const float* We2 = (const float*)d_in[3];
  const float* be2 = (const float*)d_in[4];
  const float* W1  = (const float*)d_in[5];
  const float* b1  = (const float*)d_in[6];
  const float* W2  = (const float*)d_in[7];
  const float* b2  = (const float*)d_in[8];
  const float* lA  = (const float*)d_in[9];
  const float* lB  = (const float*)d_in[10];

  float* out  = (float*)d_out;
  float* zout = out + OUT_ELEMS;                       // second tuple output
  unsigned short* wsw = (unsigned short*)d_ws;         // 512 KB bf16 W pack
  float* wsM = (float*)((char*)d_ws + WS_W_BYTES);     // 240 floats

  hipLaunchKernelGGL(k0_pack, dim3(129), dim3(256), 0, stream,
                     We1, lA, lB, wsw, wsM);
  hipLaunchKernelGGL(k1_fused, dim3(BDIM / 64), dim3(256), 0, stream,
                     x, wsw, be1, We2, be2, W1, b1, W2, b2, wsM, out, zout);
}